// Round 4
// baseline (187.081 us; speedup 1.0000x reference)
//
#include <hip/hip_runtime.h>

// SparseProductLayer:  out = x @ (M0*M1*M2)^T + bias
// Pipeline: fused CSR build (1 kernel) -> entry-wise Mc build -> x->bf16 ->
// 8-phase-style MFMA GEMM (BM=128,BN=256,BK=64, 3-deep LDS ring, counted vmcnt,
// T2 swizzle, T5 setprio). 256 blocks = 1/CU.
//
// d_ws layout (bytes):
//   [0)         Mc  bf16 [D][D]     8388608
//   [8388608)   Xb  bf16 [B][D]    16777216
//   [25165824)  CSR: off[3][2052], col[3][16384], val[3][16384]

#define BATCH 4096
#define DIM   2048
#define NNZc  16384
#define NT    256

typedef short bf16x8 __attribute__((ext_vector_type(8)));
typedef float f32x4  __attribute__((ext_vector_type(4)));

__device__ __forceinline__ unsigned short f2bf(float f) {
    unsigned u = __float_as_uint(f);
    unsigned r = (u + 0x7fffu + ((u >> 16) & 1u)) >> 16;   // RNE
    return (unsigned short)r;
}

__device__ __forceinline__ void gload16(const void* g, void* l) {
    __builtin_amdgcn_global_load_lds((const __attribute__((address_space(1))) void*)g,
                                     (__attribute__((address_space(3))) void*)l, 16, 0, 0);
}

// ---- fused CSR build: histogram + scan + scatter, one block ----
__global__ __launch_bounds__(1024) void csr_build_kernel(
        const int* __restrict__ r0, const int* __restrict__ c0, const float* __restrict__ v0,
        const int* __restrict__ r1, const int* __restrict__ c1, const float* __restrict__ v1,
        const int* __restrict__ r2, const int* __restrict__ c2, const float* __restrict__ v2,
        int* __restrict__ offb, int* __restrict__ colb, float* __restrict__ valb) {
    __shared__ int cnt[3 * 2048];
    __shared__ int part[256];
    const int t = threadIdx.x;
    for (int i = t; i < 3 * 2048; i += 1024) cnt[i] = 0;
    __syncthreads();
    for (int e = t; e < 3 * NNZc; e += 1024) {
        int m = e >> 14, i = e & (NNZc - 1);
        const int* rp = (m == 0) ? r0 : (m == 1) ? r1 : r2;
        atomicAdd(&cnt[m * 2048 + rp[i]], 1);
    }
    __syncthreads();
    for (int m = 0; m < 3; ++m) {
        if (t < 256) {
            int base = m * 2048 + t * 8, s = 0;
            #pragma unroll
            for (int i = 0; i < 8; ++i) s += cnt[base + i];
            part[t] = s;
        }
        __syncthreads();
        if (t == 0) {
            int run = 0;
            for (int i = 0; i < 256; ++i) { int v = part[i]; part[i] = run; run += v; }
        }
        __syncthreads();
        if (t < 256) {
            int base = part[t];
            #pragma unroll
            for (int i = 0; i < 8; ++i) {
                int idx = m * 2048 + t * 8 + i;
                int c = cnt[idx];
                offb[m * 2052 + t * 8 + i] = base;
                cnt[idx] = base;                  // becomes cur
                base += c;
            }
            if (t == 0) offb[m * 2052 + 2048] = NNZc;
        }
        __syncthreads();
    }
    for (int e = t; e < 3 * NNZc; e += 1024) {
        int m = e >> 14, i = e & (NNZc - 1);
        const int*   rp = (m == 0) ? r0 : (m == 1) ? r1 : r2;
        const int*   cp = (m == 0) ? c0 : (m == 1) ? c1 : c2;
        const float* vp = (m == 0) ? v0 : (m == 1) ? v1 : v2;
        int slot = atomicAdd(&cnt[m * 2048 + rp[i]], 1);
        colb[m * NNZc + slot] = cp[i];
        valb[m * NNZc + slot] = vp[i];
    }
}

// ---- Mc build: per block, RPB output rows via 3-level tree walk in LDS ----
#define RPB  2
#define PCAP 2048
__global__ __launch_bounds__(NT) void mcbuild_kernel(
        const int* __restrict__ offb, const int* __restrict__ colb,
        const float* __restrict__ valb, unsigned short* __restrict__ Mc) {
    const int* off0 = offb;              const int* off1 = offb + 2052;  const int* off2 = offb + 4104;
    const int* col0 = colb;              const int* col1 = colb + NNZc;  const int* col2 = colb + 2 * NNZc;
    const float* val0 = valb;            const float* val1 = valb + NNZc; const float* val2 = valb + 2 * NNZc;

    __shared__ float acc[RPB * DIM];
    __shared__ int   pk[PCAP];
    __shared__ float pw[PCAP];
    __shared__ int   npairs;

    const int tid = threadIdx.x;
    const int r0  = blockIdx.x * RPB;

    f32x4* az = (f32x4*)acc;
    #pragma unroll
    for (int j = tid; j < RPB * DIM / 4; j += NT) az[j] = (f32x4){0.f, 0.f, 0.f, 0.f};
    if (tid == 0) npairs = 0;
    __syncthreads();

    #pragma unroll
    for (int k = 0; k < RPB; ++k) {
        int b = off0[r0 + k], e = off0[r0 + k + 1];
        for (int i = b + tid; i < e; i += NT) {
            int   c0 = col0[i];
            float v0 = val0[i];
            int b1 = off1[c0], e1 = off1[c0 + 1];
            for (int j = b1; j < e1; ++j) {
                float w = v0 * val1[j];
                int   c1 = col1[j];
                int slot = atomicAdd(&npairs, 1);
                if (slot < PCAP) { pk[slot] = (k << 16) | c1; pw[slot] = w; }
                else {
                    int b2 = off2[c1], e2 = off2[c1 + 1];
                    for (int q = b2; q < e2; ++q)
                        atomicAdd(&acc[k * DIM + col2[q]], w * val2[q]);
                }
            }
        }
    }
    __syncthreads();

    int np = min(npairs, PCAP);
    for (int p = tid; p < np; p += NT) {
        int   k  = pk[p] >> 16, c1 = pk[p] & 0xffff;
        float w  = pw[p];
        int b2 = off2[c1], e2 = off2[c1 + 1];
        for (int q = b2; q < e2; ++q)
            atomicAdd(&acc[k * DIM + col2[q]], w * val2[q]);
    }
    __syncthreads();

    #pragma unroll
    for (int k = 0; k < RPB; ++k) {
        unsigned short o[8];
        #pragma unroll
        for (int jj = 0; jj < 8; ++jj) o[jj] = f2bf(acc[k * DIM + tid * 8 + jj]);
        *(ulonglong2*)(Mc + (size_t)(r0 + k) * DIM + tid * 8) = *(ulonglong2*)o;
    }
}

// ---- x (f32) -> bf16 ----
__global__ void xconv_kernel(const float* __restrict__ x, unsigned short* __restrict__ Xb) {
    size_t i = ((size_t)blockIdx.x * NT + threadIdx.x) * 8;
    float4 a = *(const float4*)(x + i);
    float4 b = *(const float4*)(x + i + 4);
    unsigned short o[8] = {f2bf(a.x), f2bf(a.y), f2bf(a.z), f2bf(a.w),
                           f2bf(b.x), f2bf(b.y), f2bf(b.z), f2bf(b.w)};
    *(ulonglong2*)(Xb + i) = *(ulonglong2*)o;
}

// ---- GEMM: C = Xb(4096x2048) @ Mc^T + bias ----
// BM=128, BN=256, BK=64, 8 waves (2M x 4N), 3-slot LDS ring, 4 phases/K-step,
// counted vmcnt(6), LDS XOR-swizzle byte^=((row&7)<<4), setprio around MFMA.
#define BM 128
#define BN 256
#define BK 64
#define NSK (DIM / BK)                      // 32
#define A_BYTES (BM * BK * 2)               // 16384
#define B_BYTES (BN * BK * 2)               // 32768
#define SLOT_BYTES (A_BYTES + B_BYTES)      // 49152
#define GEMM_LDS (3 * SLOT_BYTES)           // 147456

__global__ __launch_bounds__(512, 2) void gemm8(
        const unsigned short* __restrict__ A,   // Xb [4096][2048]
        const unsigned short* __restrict__ Bm,  // Mc [2048][2048]
        const float* __restrict__ bias,
        float* __restrict__ C) {
    extern __shared__ char smem[];
    const int tid = threadIdx.x;
    const int l = tid & 63, w = tid >> 6;
    const int wm = w & 1, wn = w >> 1;          // 2 x 4 wave grid
    const int tileM = blockIdx.y * BM;
    const int tileN = blockIdx.x * BN;

    // per-lane swizzled LDS read offsets (k-slice 0/1); swizzle ^((row&7)<<4), row&7 == l&7
    const int lo0 = (((l >> 4) * 16) ^ ((l & 7) << 4));
    const int lo1 = ((64 + (l >> 4) * 16) ^ ((l & 7) << 4));
    const int rowb = (l & 15) * 128;

    // stage sources: thread t covers LDS row t>>3, 16B chunk t&7; source chunk pre-swizzled
    const int t8 = tid >> 3;                                  // 0..63
    const int chsw = ((tid & 7) ^ (t8 & 7)) * 8;              // bf16 elements
    const unsigned short* aS0 = A  + (size_t)(tileM +       t8) * DIM + chsw;   // A half0
    const unsigned short* aS1 = A  + (size_t)(tileM +  64 + t8) * DIM + chsw;   // A half1
    const unsigned short* bS0 = Bm + (size_t)(tileN +       t8) * DIM + chsw;   // B rows   0- 63
    const unsigned short* bS1 = Bm + (size_t)(tileN +  64 + t8) * DIM + chsw;   //         64-127
    const unsigned short* bS2 = Bm + (size_t)(tileN + 128 + t8) * DIM + chsw;   //        128-191
    const unsigned short* bS3 = Bm + (size_t)(tileN + 192 + t8) * DIM + chsw;   //        192-255
    const int wdst = w * 1024;

#define STG_A0(z, s) gload16(aS0 + (size_t)(s) * BK, (z) + 0 * 8192 + wdst)
#define STG_A1(z, s) gload16(aS1 + (size_t)(s) * BK, (z) + 1 * 8192 + wdst)
#define STG_B0(z, s) gload16(bS0 + (size_t)(s) * BK, (z) + A_BYTES + 0 * 8192 + wdst)
#define STG_B1(z, s) gload16(bS1 + (size_t)(s) * BK, (z) + A_BYTES + 1 * 8192 + wdst)
#define STG_B2(z, s) gload16(bS2 + (size_t)(s) * BK, (z) + A_BYTES + 2 * 8192 + wdst)
#define STG_B3(z, s) gload16(bS3 + (size_t)(s) * BK, (z) + A_BYTES + 3 * 8192 + wdst)

    char* p0 = smem;                    // K-step s
    char* p1 = smem + SLOT_BYTES;       // s+1
    char* p2 = smem + 2 * SLOT_BYTES;   // s+2 (stage target)

    // prologue: stage K-steps 0 and 1 (6 loads each); wait K0, allow K1 in flight
    STG_B0(p0, 0); STG_B1(p0, 0); STG_B2(p0, 0); STG_B3(p0, 0); STG_A0(p0, 0); STG_A1(p0, 0);
    STG_B0(p1, 1); STG_B1(p1, 1); STG_B2(p1, 1); STG_B3(p1, 1); STG_A0(p1, 1); STG_A1(p1, 1);
    asm volatile("s_waitcnt vmcnt(6)" ::: "memory");
    __builtin_amdgcn_s_barrier();

    f32x4 acc[4][4] = {};

    for (int s = 0; s < NSK; ++s) {
        const bool pf = (s + 2 < NSK);
        #pragma unroll
        for (int q = 0; q < 4; ++q) {
            // ds_read current subtile (swizzled)
            const char* ab = p0 + wm * 8192 + q * 2048 + rowb;
            bf16x8 a0 = *(const bf16x8*)(ab + lo0);
            bf16x8 a1 = *(const bf16x8*)(ab + lo1);
            bf16x8 b0[4], b1[4];
            #pragma unroll
            for (int j = 0; j < 4; ++j) {
                const char* bb = p0 + A_BYTES + wn * 8192 + j * 2048 + rowb;
                b0[j] = *(const bf16x8*)(bb + lo0);
                b1[j] = *(const bf16x8*)(bb + lo1);
            }
            // stage K-step s+2 into p2 (slot freed at end of K-step s-1)
            if (q == 0 && pf) { STG_B0(p2, s + 2); STG_B1(p2, s + 2); }
            if (q == 1 && pf) { STG_B2(p2, s + 2); STG_B3(p2, s + 2); }
            if (q == 2 && pf) { STG_A0(p2, s + 2); STG_A1(p2, s + 2); }
            __builtin_amdgcn_sched_barrier(0);
            __builtin_amdgcn_s_barrier();
            asm volatile("s_waitcnt lgkmcnt(0)" ::: "memory");
            __builtin_amdgcn_sched_barrier(0);
            __builtin_amdgcn_s_setprio(1);
            #pragma unroll
            for (int j = 0; j < 4; ++j) {
                acc[q][j] = __builtin_amdgcn_mfma_f32_16x16x32_bf16(a0, b0[j], acc[q][j], 0, 0, 0);
                acc[q][j] = __builtin_amdgcn_mfma_f32_16x16x32_bf16(a1, b1[j], acc[q][j], 0, 0, 0);
            }
            __builtin_amdgcn_s_setprio(0);
            if (q == 3) {
                if (pf) asm volatile("s_waitcnt vmcnt(6)" ::: "memory");
                else    asm volatile("s_waitcnt vmcnt(0)" ::: "memory");
            }
            __builtin_amdgcn_sched_barrier(0);
            __builtin_amdgcn_s_barrier();
        }
        char* t = p0; p0 = p1; p1 = p2; p2 = t;
    }

    // epilogue: C = acc + bias
    #pragma unroll
    for (int j = 0; j < 4; ++j) {
        int col = tileN + wn * 64 + j * 16 + (l & 15);
        float bj = bias[col];
        #pragma unroll
        for (int i = 0; i < 4; ++i) {
            int rw = tileM + wm * 64 + i * 16 + (l >> 4) * 4;
            #pragma unroll
            for (int r = 0; r < 4; ++r)
                C[(size_t)(rw + r) * DIM + col] = acc[i][j][r] + bj;
        }
    }
}

extern "C" void kernel_launch(void* const* d_in, const int* in_sizes, int n_in,
                              void* d_out, int out_size, void* d_ws, size_t ws_size,
                              hipStream_t stream) {
    const float* x     = (const float*)d_in[0];
    const int*   rows0 = (const int*)  d_in[1];
    const int*   cols0 = (const int*)  d_in[2];
    const float* vals0 = (const float*)d_in[3];
    const int*   rows1 = (const int*)  d_in[4];
    const int*   cols1 = (const int*)  d_in[5];
    const float* vals1 = (const float*)d_in[6];
    const int*   rows2 = (const int*)  d_in[7];
    const int*   cols2 = (const int*)  d_in[8];
    const float* vals2 = (const float*)d_in[9];
    const float* bias  = (const float*)d_in[10];
    float* out = (float*)d_out;

    char* ws = (char*)d_ws;
    unsigned short* Mc = (unsigned short*)ws;                 // 8 MB
    unsigned short* Xb = (unsigned short*)(ws + 8388608);     // 16 MB
    int*   offb = (int*)(ws + 25165824);      // 3 * 2052
    int*   colb = offb + 3 * 2052;            // 3 * 16384
    float* valb = (float*)(colb + 3 * NNZc);  // 3 * 16384

    csr_build_kernel<<<1, 1024, 0, stream>>>(rows0, cols0, vals0,
                                             rows1, cols1, vals1,
                                             rows2, cols2, vals2,
                                             offb, colb, valb);
    mcbuild_kernel<<<DIM / RPB, NT, 0, stream>>>(offb, colb, valb, Mc);
    xconv_kernel<<<(BATCH * DIM) / (NT * 8), NT, 0, stream>>>(x, Xb);

    (void)hipFuncSetAttribute((const void*)gemm8,
                              hipFuncAttributeMaxDynamicSharedMemorySize, GEMM_LDS);
    dim3 ggrid(DIM / BN, BATCH / BM);   // 8 x 32 = 256 blocks
    gemm8<<<ggrid, 512, GEMM_LDS, stream>>>(Xb, Mc, bias, out);
}

// Round 5
// 95.486 us; speedup vs baseline: 1.9592x; 1.9592x over previous
//
#include <hip/hip_runtime.h>

// SparseProductLayer:  out = x @ (M0*M1*M2)^T + bias
// Pipeline: multi-block CSR build (hist/scan/scatter) -> entry-wise Mc build ->
// x->bf16 -> 8-phase MFMA GEMM (BM=128,BN=256,BK=64, 3-deep LDS ring,
// counted vmcnt, T2 swizzle, T5 setprio). 256 blocks = 1/CU.
//
// d_ws layout (bytes):
//   [0)         Mc  bf16 [D][D]     8388608
//   [8388608)   Xb  bf16 [B][D]    16777216
//   [25165824)  CSR: off[3][2052], cur[3][2048], col[3][16384], val[3][16384]

#define BATCH 4096
#define DIM   2048
#define NNZc  16384
#define NT    256

typedef short bf16x8 __attribute__((ext_vector_type(8)));
typedef float f32x4  __attribute__((ext_vector_type(4)));

__device__ __forceinline__ unsigned short f2bf(float f) {
    unsigned u = __float_as_uint(f);
    unsigned r = (u + 0x7fffu + ((u >> 16) & 1u)) >> 16;   // RNE
    return (unsigned short)r;
}

__device__ __forceinline__ void gload16(const void* g, void* l) {
    __builtin_amdgcn_global_load_lds((const __attribute__((address_space(1))) void*)g,
                                     (__attribute__((address_space(3))) void*)l, 16, 0, 0);
}

// ---- CSR build: histogram (all 3 matrices, multi-block) ----
__global__ void hist_kernel(const int* __restrict__ rows0, const int* __restrict__ rows1,
                            const int* __restrict__ rows2, int* __restrict__ cur) {
    int e = blockIdx.x * NT + threadIdx.x;          // 0 .. 3*NNZ
    int m = e >> 14, i = e & (NNZc - 1);
    const int* rp = (m == 0) ? rows0 : (m == 1) ? rows1 : rows2;
    atomicAdd(&cur[m * DIM + rp[i]], 1);
}

// ---- CSR build: exclusive scan of 2048 counts (one block per matrix) ----
__global__ void scan_kernel(int* __restrict__ curb, int* __restrict__ offb) {
    int* cur = curb + blockIdx.x * DIM;
    int* off = offb + blockIdx.x * 2052;
    __shared__ int part[NT];
    int t = threadIdx.x;
    int c[8]; int s = 0;
    #pragma unroll
    for (int i = 0; i < 8; ++i) { c[i] = cur[t * 8 + i]; s += c[i]; }
    part[t] = s;
    __syncthreads();
    if (t == 0) {
        int run = 0;
        for (int i = 0; i < NT; ++i) { int v = part[i]; part[i] = run; run += v; }
    }
    __syncthreads();
    int base = part[t];
    #pragma unroll
    for (int i = 0; i < 8; ++i) {
        int idx = t * 8 + i;
        off[idx] = base; cur[idx] = base; base += c[i];
    }
    if (t == 0) off[DIM] = NNZc;
}

// ---- CSR build: scatter entries into row buckets ----
__global__ void scatter_kernel(const int* __restrict__ rows0, const int* __restrict__ cols0,
                               const float* __restrict__ vals0,
                               const int* __restrict__ rows1, const int* __restrict__ cols1,
                               const float* __restrict__ vals1,
                               const int* __restrict__ rows2, const int* __restrict__ cols2,
                               const float* __restrict__ vals2,
                               int* __restrict__ cur,
                               int* __restrict__ colb, float* __restrict__ valb) {
    int e = blockIdx.x * NT + threadIdx.x;
    int m = e >> 14, i = e & (NNZc - 1);
    const int*   rp = (m == 0) ? rows0 : (m == 1) ? rows1 : rows2;
    const int*   cp = (m == 0) ? cols0 : (m == 1) ? cols1 : cols2;
    const float* vp = (m == 0) ? vals0 : (m == 1) ? vals1 : vals2;
    int slot = atomicAdd(&cur[m * DIM + rp[i]], 1);
    colb[m * NNZc + slot] = cp[i];
    valb[m * NNZc + slot] = vp[i];
}

// ---- Mc build: per block, RPB output rows via 3-level tree walk in LDS ----
#define RPB  2
#define PCAP 2048
__global__ __launch_bounds__(NT) void mcbuild_kernel(
        const int* __restrict__ offb, const int* __restrict__ colb,
        const float* __restrict__ valb, unsigned short* __restrict__ Mc) {
    const int* off0 = offb;              const int* off1 = offb + 2052;  const int* off2 = offb + 4104;
    const int* col0 = colb;              const int* col1 = colb + NNZc;  const int* col2 = colb + 2 * NNZc;
    const float* val0 = valb;            const float* val1 = valb + NNZc; const float* val2 = valb + 2 * NNZc;

    __shared__ float acc[RPB * DIM];
    __shared__ int   pk[PCAP];
    __shared__ float pw[PCAP];
    __shared__ int   npairs;

    const int tid = threadIdx.x;
    const int r0  = blockIdx.x * RPB;

    f32x4* az = (f32x4*)acc;
    #pragma unroll
    for (int j = tid; j < RPB * DIM / 4; j += NT) az[j] = (f32x4){0.f, 0.f, 0.f, 0.f};
    if (tid == 0) npairs = 0;
    __syncthreads();

    #pragma unroll
    for (int k = 0; k < RPB; ++k) {
        int b = off0[r0 + k], e = off0[r0 + k + 1];
        for (int i = b + tid; i < e; i += NT) {
            int   c0 = col0[i];
            float v0 = val0[i];
            int b1 = off1[c0], e1 = off1[c0 + 1];
            for (int j = b1; j < e1; ++j) {
                float w = v0 * val1[j];
                int   c1 = col1[j];
                int slot = atomicAdd(&npairs, 1);
                if (slot < PCAP) { pk[slot] = (k << 16) | c1; pw[slot] = w; }
                else {
                    int b2 = off2[c1], e2 = off2[c1 + 1];
                    for (int q = b2; q < e2; ++q)
                        atomicAdd(&acc[k * DIM + col2[q]], w * val2[q]);
                }
            }
        }
    }
    __syncthreads();

    int np = min(npairs, PCAP);
    for (int p = tid; p < np; p += NT) {
        int   k  = pk[p] >> 16, c1 = pk[p] & 0xffff;
        float w  = pw[p];
        int b2 = off2[c1], e2 = off2[c1 + 1];
        for (int q = b2; q < e2; ++q)
            atomicAdd(&acc[k * DIM + col2[q]], w * val2[q]);
    }
    __syncthreads();

    #pragma unroll
    for (int k = 0; k < RPB; ++k) {
        unsigned short o[8];
        #pragma unroll
        for (int jj = 0; jj < 8; ++jj) o[jj] = f2bf(acc[k * DIM + tid * 8 + jj]);
        *(ulonglong2*)(Mc + (size_t)(r0 + k) * DIM + tid * 8) = *(ulonglong2*)o;
    }
}

// ---- x (f32) -> bf16 ----
__global__ void xconv_kernel(const float* __restrict__ x, unsigned short* __restrict__ Xb) {
    size_t i = ((size_t)blockIdx.x * NT + threadIdx.x) * 8;
    float4 a = *(const float4*)(x + i);
    float4 b = *(const float4*)(x + i + 4);
    unsigned short o[8] = {f2bf(a.x), f2bf(a.y), f2bf(a.z), f2bf(a.w),
                           f2bf(b.x), f2bf(b.y), f2bf(b.z), f2bf(b.w)};
    *(ulonglong2*)(Xb + i) = *(ulonglong2*)o;
}

// ---- GEMM: C = Xb(4096x2048) @ Mc^T + bias ----
// BM=128, BN=256, BK=64, 8 waves (2M x 4N), 3-slot LDS ring, 4 phases/K-step,
// counted vmcnt(6), LDS XOR-swizzle byte^=((row&7)<<4), setprio around MFMA.
#define BM 128
#define BN 256
#define BK 64
#define NSK (DIM / BK)                      // 32
#define A_BYTES (BM * BK * 2)               // 16384
#define B_BYTES (BN * BK * 2)               // 32768
#define SLOT_BYTES (A_BYTES + B_BYTES)      // 49152
#define GEMM_LDS (3 * SLOT_BYTES)           // 147456

__global__ __launch_bounds__(512, 2) void gemm8(
        const unsigned short* __restrict__ A,   // Xb [4096][2048]
        const unsigned short* __restrict__ Bm,  // Mc [2048][2048]
        const float* __restrict__ bias,
        float* __restrict__ C) {
    extern __shared__ char smem[];
    const int tid = threadIdx.x;
    const int l = tid & 63, w = tid >> 6;
    const int wm = w & 1, wn = w >> 1;          // 2 x 4 wave grid
    const int tileM = blockIdx.y * BM;
    const int tileN = blockIdx.x * BN;

    // per-lane swizzled LDS read offsets (k-slice 0/1); swizzle ^((row&7)<<4), row&7 == l&7
    const int lo0 = (((l >> 4) * 16) ^ ((l & 7) << 4));
    const int lo1 = ((64 + (l >> 4) * 16) ^ ((l & 7) << 4));
    const int rowb = (l & 15) * 128;

    // stage sources: thread t covers LDS row t>>3, 16B chunk t&7; source chunk pre-swizzled
    const int t8 = tid >> 3;                                  // 0..63
    const int chsw = ((tid & 7) ^ (t8 & 7)) * 8;              // bf16 elements
    const unsigned short* aS0 = A  + (size_t)(tileM +       t8) * DIM + chsw;   // A half0
    const unsigned short* aS1 = A  + (size_t)(tileM +  64 + t8) * DIM + chsw;   // A half1
    const unsigned short* bS0 = Bm + (size_t)(tileN +       t8) * DIM + chsw;   // B rows   0- 63
    const unsigned short* bS1 = Bm + (size_t)(tileN +  64 + t8) * DIM + chsw;   //         64-127
    const unsigned short* bS2 = Bm + (size_t)(tileN + 128 + t8) * DIM + chsw;   //        128-191
    const unsigned short* bS3 = Bm + (size_t)(tileN + 192 + t8) * DIM + chsw;   //        192-255
    const int wdst = w * 1024;

#define STG_A0(z, s) gload16(aS0 + (size_t)(s) * BK, (z) + 0 * 8192 + wdst)
#define STG_A1(z, s) gload16(aS1 + (size_t)(s) * BK, (z) + 1 * 8192 + wdst)
#define STG_B0(z, s) gload16(bS0 + (size_t)(s) * BK, (z) + A_BYTES + 0 * 8192 + wdst)
#define STG_B1(z, s) gload16(bS1 + (size_t)(s) * BK, (z) + A_BYTES + 1 * 8192 + wdst)
#define STG_B2(z, s) gload16(bS2 + (size_t)(s) * BK, (z) + A_BYTES + 2 * 8192 + wdst)
#define STG_B3(z, s) gload16(bS3 + (size_t)(s) * BK, (z) + A_BYTES + 3 * 8192 + wdst)

    char* p0 = smem;                    // K-step s
    char* p1 = smem + SLOT_BYTES;       // s+1
    char* p2 = smem + 2 * SLOT_BYTES;   // s+2 (stage target)

    // prologue: stage K-steps 0 and 1 (6 loads each); wait K0, allow K1 in flight
    STG_B0(p0, 0); STG_B1(p0, 0); STG_B2(p0, 0); STG_B3(p0, 0); STG_A0(p0, 0); STG_A1(p0, 0);
    STG_B0(p1, 1); STG_B1(p1, 1); STG_B2(p1, 1); STG_B3(p1, 1); STG_A0(p1, 1); STG_A1(p1, 1);
    asm volatile("s_waitcnt vmcnt(6)" ::: "memory");
    __builtin_amdgcn_s_barrier();

    f32x4 acc[4][4] = {};

    for (int s = 0; s < NSK; ++s) {
        const bool pf = (s + 2 < NSK);
        #pragma unroll
        for (int q = 0; q < 4; ++q) {
            // ds_read current subtile (swizzled)
            const char* ab = p0 + wm * 8192 + q * 2048 + rowb;
            bf16x8 a0 = *(const bf16x8*)(ab + lo0);
            bf16x8 a1 = *(const bf16x8*)(ab + lo1);
            bf16x8 b0[4], b1[4];
            #pragma unroll
            for (int j = 0; j < 4; ++j) {
                const char* bb = p0 + A_BYTES + wn * 8192 + j * 2048 + rowb;
                b0[j] = *(const bf16x8*)(bb + lo0);
                b1[j] = *(const bf16x8*)(bb + lo1);
            }
            // stage K-step s+2 into p2 (slot freed at end of K-step s-1)
            if (q == 0 && pf) { STG_B0(p2, s + 2); STG_B1(p2, s + 2); }
            if (q == 1 && pf) { STG_B2(p2, s + 2); STG_B3(p2, s + 2); }
            if (q == 2 && pf) { STG_A0(p2, s + 2); STG_A1(p2, s + 2); }
            __builtin_amdgcn_sched_barrier(0);
            __builtin_amdgcn_s_barrier();
            asm volatile("s_waitcnt lgkmcnt(0)" ::: "memory");
            __builtin_amdgcn_sched_barrier(0);
            __builtin_amdgcn_s_setprio(1);
            #pragma unroll
            for (int j = 0; j < 4; ++j) {
                acc[q][j] = __builtin_amdgcn_mfma_f32_16x16x32_bf16(a0, b0[j], acc[q][j], 0, 0, 0);
                acc[q][j] = __builtin_amdgcn_mfma_f32_16x16x32_bf16(a1, b1[j], acc[q][j], 0, 0, 0);
            }
            __builtin_amdgcn_s_setprio(0);
            if (q == 3) {
                if (pf) asm volatile("s_waitcnt vmcnt(6)" ::: "memory");
                else    asm volatile("s_waitcnt vmcnt(0)" ::: "memory");
            }
            __builtin_amdgcn_sched_barrier(0);
            __builtin_amdgcn_s_barrier();
        }
        char* t = p0; p0 = p1; p1 = p2; p2 = t;
    }

    // epilogue: C = acc + bias
    #pragma unroll
    for (int j = 0; j < 4; ++j) {
        int col = tileN + wn * 64 + j * 16 + (l & 15);
        float bj = bias[col];
        #pragma unroll
        for (int i = 0; i < 4; ++i) {
            int rw = tileM + wm * 64 + i * 16 + (l >> 4) * 4;
            #pragma unroll
            for (int r = 0; r < 4; ++r)
                C[(size_t)(rw + r) * DIM + col] = acc[i][j][r] + bj;
        }
    }
}

extern "C" void kernel_launch(void* const* d_in, const int* in_sizes, int n_in,
                              void* d_out, int out_size, void* d_ws, size_t ws_size,
                              hipStream_t stream) {
    const float* x     = (const float*)d_in[0];
    const int*   rows0 = (const int*)  d_in[1];
    const int*   cols0 = (const int*)  d_in[2];
    const float* vals0 = (const float*)d_in[3];
    const int*   rows1 = (const int*)  d_in[4];
    const int*   cols1 = (const int*)  d_in[5];
    const float* vals1 = (const float*)d_in[6];
    const int*   rows2 = (const int*)  d_in[7];
    const int*   cols2 = (const int*)  d_in[8];
    const float* vals2 = (const float*)d_in[9];
    const float* bias  = (const float*)d_in[10];
    float* out = (float*)d_out;

    char* ws = (char*)d_ws;
    unsigned short* Mc = (unsigned short*)ws;                 // 8 MB
    unsigned short* Xb = (unsigned short*)(ws + 8388608);     // 16 MB
    int*   offb = (int*)(ws + 25165824);      // 3 * 2052
    int*   curb = offb + 3 * 2052;            // 3 * 2048
    int*   colb = curb + 3 * DIM;             // 3 * 16384
    float* valb = (float*)(colb + 3 * NNZc);  // 3 * 16384

    hipMemsetAsync(curb, 0, 3 * DIM * sizeof(int), stream);

    hist_kernel<<<3 * NNZc / NT, NT, 0, stream>>>(rows0, rows1, rows2, curb);
    scan_kernel<<<3, NT, 0, stream>>>(curb, offb);
    scatter_kernel<<<3 * NNZc / NT, NT, 0, stream>>>(rows0, cols0, vals0,
                                                     rows1, cols1, vals1,
                                                     rows2, cols2, vals2,
                                                     curb, colb, valb);
    mcbuild_kernel<<<DIM / RPB, NT, 0, stream>>>(offb, colb, valb, Mc);
    xconv_kernel<<<(BATCH * DIM) / (NT * 8), NT, 0, stream>>>(x, Xb);

    (void)hipFuncSetAttribute((const void*)gemm8,
                              hipFuncAttributeMaxDynamicSharedMemorySize, GEMM_LDS);
    dim3 ggrid(DIM / BN, BATCH / BM);   // 8 x 32 = 256 blocks
    gemm8<<<ggrid, 512, GEMM_LDS, stream>>>(Xb, Mc, bias, out);
}

// Round 6
// 85.476 us; speedup vs baseline: 2.1887x; 1.1171x over previous
//
#include <hip/hip_runtime.h>

// SparseProductLayer:  out = x @ (M0*M1*M2)^T + bias
// Pipeline: multi-block CSR build (hist/scan/scatter) -> entry-wise Mc build ->
// x->bf16 -> MFMA GEMM (BM=128,BN=256,BK=64, 3-deep LDS ring, counted vmcnt,
// T2 swizzle, T5 setprio; 2 phases/K-step, no redundant B-frag re-reads).
// 256 blocks = 1/CU.
//
// d_ws layout (bytes):
//   [0)         Mc  bf16 [D][D]     8388608
//   [8388608)   Xb  bf16 [B][D]    16777216
//   [25165824)  CSR: off[3][2052], cur[3][2048], col[3][16384], val[3][16384]

#define BATCH 4096
#define DIM   2048
#define NNZc  16384
#define NT    256

typedef short bf16x8 __attribute__((ext_vector_type(8)));
typedef float f32x4  __attribute__((ext_vector_type(4)));

__device__ __forceinline__ unsigned short f2bf(float f) {
    unsigned u = __float_as_uint(f);
    unsigned r = (u + 0x7fffu + ((u >> 16) & 1u)) >> 16;   // RNE
    return (unsigned short)r;
}

__device__ __forceinline__ void gload16(const void* g, void* l) {
    __builtin_amdgcn_global_load_lds((const __attribute__((address_space(1))) void*)g,
                                     (__attribute__((address_space(3))) void*)l, 16, 0, 0);
}

// ---- CSR build: histogram (all 3 matrices, multi-block) ----
__global__ void hist_kernel(const int* __restrict__ rows0, const int* __restrict__ rows1,
                            const int* __restrict__ rows2, int* __restrict__ cur) {
    int e = blockIdx.x * NT + threadIdx.x;          // 0 .. 3*NNZ
    int m = e >> 14, i = e & (NNZc - 1);
    const int* rp = (m == 0) ? rows0 : (m == 1) ? rows1 : rows2;
    atomicAdd(&cur[m * DIM + rp[i]], 1);
}

// ---- CSR build: exclusive scan of 2048 counts (one block per matrix) ----
__global__ void scan_kernel(int* __restrict__ curb, int* __restrict__ offb) {
    int* cur = curb + blockIdx.x * DIM;
    int* off = offb + blockIdx.x * 2052;
    __shared__ int part[NT];
    int t = threadIdx.x;
    int c[8]; int s = 0;
    #pragma unroll
    for (int i = 0; i < 8; ++i) { c[i] = cur[t * 8 + i]; s += c[i]; }
    part[t] = s;
    __syncthreads();
    if (t == 0) {
        int run = 0;
        for (int i = 0; i < NT; ++i) { int v = part[i]; part[i] = run; run += v; }
    }
    __syncthreads();
    int base = part[t];
    #pragma unroll
    for (int i = 0; i < 8; ++i) {
        int idx = t * 8 + i;
        off[idx] = base; cur[idx] = base; base += c[i];
    }
    if (t == 0) off[DIM] = NNZc;
}

// ---- CSR build: scatter entries into row buckets ----
__global__ void scatter_kernel(const int* __restrict__ rows0, const int* __restrict__ cols0,
                               const float* __restrict__ vals0,
                               const int* __restrict__ rows1, const int* __restrict__ cols1,
                               const float* __restrict__ vals1,
                               const int* __restrict__ rows2, const int* __restrict__ cols2,
                               const float* __restrict__ vals2,
                               int* __restrict__ cur,
                               int* __restrict__ colb, float* __restrict__ valb) {
    int e = blockIdx.x * NT + threadIdx.x;
    int m = e >> 14, i = e & (NNZc - 1);
    const int*   rp = (m == 0) ? rows0 : (m == 1) ? rows1 : rows2;
    const int*   cp = (m == 0) ? cols0 : (m == 1) ? cols1 : cols2;
    const float* vp = (m == 0) ? vals0 : (m == 1) ? vals1 : vals2;
    int slot = atomicAdd(&cur[m * DIM + rp[i]], 1);
    colb[m * NNZc + slot] = cp[i];
    valb[m * NNZc + slot] = vp[i];
}

// ---- Mc build: per block, RPB output rows via 3-level tree walk in LDS ----
#define RPB  2
#define PCAP 2048
__global__ __launch_bounds__(NT) void mcbuild_kernel(
        const int* __restrict__ offb, const int* __restrict__ colb,
        const float* __restrict__ valb, unsigned short* __restrict__ Mc) {
    const int* off0 = offb;              const int* off1 = offb + 2052;  const int* off2 = offb + 4104;
    const int* col0 = colb;              const int* col1 = colb + NNZc;  const int* col2 = colb + 2 * NNZc;
    const float* val0 = valb;            const float* val1 = valb + NNZc; const float* val2 = valb + 2 * NNZc;

    __shared__ float acc[RPB * DIM];
    __shared__ int   pk[PCAP];
    __shared__ float pw[PCAP];
    __shared__ int   npairs;

    const int tid = threadIdx.x;
    const int r0  = blockIdx.x * RPB;

    f32x4* az = (f32x4*)acc;
    #pragma unroll
    for (int j = tid; j < RPB * DIM / 4; j += NT) az[j] = (f32x4){0.f, 0.f, 0.f, 0.f};
    if (tid == 0) npairs = 0;
    __syncthreads();

    #pragma unroll
    for (int k = 0; k < RPB; ++k) {
        int b = off0[r0 + k], e = off0[r0 + k + 1];
        for (int i = b + tid; i < e; i += NT) {
            int   c0 = col0[i];
            float v0 = val0[i];
            int b1 = off1[c0], e1 = off1[c0 + 1];
            for (int j = b1; j < e1; ++j) {
                float w = v0 * val1[j];
                int   c1 = col1[j];
                int slot = atomicAdd(&npairs, 1);
                if (slot < PCAP) { pk[slot] = (k << 16) | c1; pw[slot] = w; }
                else {
                    int b2 = off2[c1], e2 = off2[c1 + 1];
                    for (int q = b2; q < e2; ++q)
                        atomicAdd(&acc[k * DIM + col2[q]], w * val2[q]);
                }
            }
        }
    }
    __syncthreads();

    int np = min(npairs, PCAP);
    for (int p = tid; p < np; p += NT) {
        int   k  = pk[p] >> 16, c1 = pk[p] & 0xffff;
        float w  = pw[p];
        int b2 = off2[c1], e2 = off2[c1 + 1];
        for (int q = b2; q < e2; ++q)
            atomicAdd(&acc[k * DIM + col2[q]], w * val2[q]);
    }
    __syncthreads();

    #pragma unroll
    for (int k = 0; k < RPB; ++k) {
        unsigned short o[8];
        #pragma unroll
        for (int jj = 0; jj < 8; ++jj) o[jj] = f2bf(acc[k * DIM + tid * 8 + jj]);
        *(ulonglong2*)(Mc + (size_t)(r0 + k) * DIM + tid * 8) = *(ulonglong2*)o;
    }
}

// ---- x (f32) -> bf16 ----
__global__ void xconv_kernel(const float* __restrict__ x, unsigned short* __restrict__ Xb) {
    size_t i = ((size_t)blockIdx.x * NT + threadIdx.x) * 8;
    float4 a = *(const float4*)(x + i);
    float4 b = *(const float4*)(x + i + 4);
    unsigned short o[8] = {f2bf(a.x), f2bf(a.y), f2bf(a.z), f2bf(a.w),
                           f2bf(b.x), f2bf(b.y), f2bf(b.z), f2bf(b.w)};
    *(ulonglong2*)(Xb + i) = *(ulonglong2*)o;
}

// ---- GEMM: C = Xb(4096x2048) @ Mc^T + bias ----
// BM=128, BN=256, BK=64, 8 waves (2M x 4N), 3-slot LDS ring, 2 phases/K-step,
// 16 distinct ds_read_b128 per K-step per wave (no redundant B re-reads),
// counted vmcnt(6), LDS XOR-swizzle byte^=((row&7)<<4), setprio around MFMA.
#define BM 128
#define BN 256
#define BK 64
#define NSK (DIM / BK)                      // 32
#define A_BYTES (BM * BK * 2)               // 16384
#define B_BYTES (BN * BK * 2)               // 32768
#define SLOT_BYTES (A_BYTES + B_BYTES)      // 49152
#define GEMM_LDS (3 * SLOT_BYTES)           // 147456

__global__ __launch_bounds__(512, 2) void gemm8(
        const unsigned short* __restrict__ A,   // Xb [4096][2048]
        const unsigned short* __restrict__ Bm,  // Mc [2048][2048]
        const float* __restrict__ bias,
        float* __restrict__ C) {
    extern __shared__ char smem[];
    const int tid = threadIdx.x;
    const int l = tid & 63, w = tid >> 6;
    const int wm = w & 1, wn = w >> 1;          // 2 x 4 wave grid
    const int tileM = blockIdx.y * BM;
    const int tileN = blockIdx.x * BN;

    // per-lane swizzled LDS read offsets (k-slice 0/1); swizzle ^((row&7)<<4), row&7 == l&7
    const int lo0 = (((l >> 4) * 16) ^ ((l & 7) << 4));
    const int lo1 = ((64 + (l >> 4) * 16) ^ ((l & 7) << 4));
    const int rowb = (l & 15) * 128;

    // stage sources: thread t covers LDS row t>>3, 16B chunk t&7; source chunk pre-swizzled
    const int t8 = tid >> 3;                                  // 0..63
    const int chsw = ((tid & 7) ^ (t8 & 7)) * 8;              // bf16 elements
    const unsigned short* aS0 = A  + (size_t)(tileM +       t8) * DIM + chsw;   // A half0
    const unsigned short* aS1 = A  + (size_t)(tileM +  64 + t8) * DIM + chsw;   // A half1
    const unsigned short* bS0 = Bm + (size_t)(tileN +       t8) * DIM + chsw;   // B rows   0- 63
    const unsigned short* bS1 = Bm + (size_t)(tileN +  64 + t8) * DIM + chsw;   //         64-127
    const unsigned short* bS2 = Bm + (size_t)(tileN + 128 + t8) * DIM + chsw;   //        128-191
    const unsigned short* bS3 = Bm + (size_t)(tileN + 192 + t8) * DIM + chsw;   //        192-255
    const int wdst = w * 1024;

#define STG_A0(z, s) gload16(aS0 + (size_t)(s) * BK, (z) + 0 * 8192 + wdst)
#define STG_A1(z, s) gload16(aS1 + (size_t)(s) * BK, (z) + 1 * 8192 + wdst)
#define STG_B0(z, s) gload16(bS0 + (size_t)(s) * BK, (z) + A_BYTES + 0 * 8192 + wdst)
#define STG_B1(z, s) gload16(bS1 + (size_t)(s) * BK, (z) + A_BYTES + 1 * 8192 + wdst)
#define STG_B2(z, s) gload16(bS2 + (size_t)(s) * BK, (z) + A_BYTES + 2 * 8192 + wdst)
#define STG_B3(z, s) gload16(bS3 + (size_t)(s) * BK, (z) + A_BYTES + 3 * 8192 + wdst)

    char* p0 = smem;                    // K-step s
    char* p1 = smem + SLOT_BYTES;       // s+1
    char* p2 = smem + 2 * SLOT_BYTES;   // s+2 (stage target)

    // prologue: stage K-steps 0 and 1 (6 loads each); wait K0, allow K1 in flight
    STG_B0(p0, 0); STG_B1(p0, 0); STG_B2(p0, 0); STG_B3(p0, 0); STG_A0(p0, 0); STG_A1(p0, 0);
    STG_B0(p1, 1); STG_B1(p1, 1); STG_B2(p1, 1); STG_B3(p1, 1); STG_A0(p1, 1); STG_A1(p1, 1);
    asm volatile("s_waitcnt vmcnt(6)" ::: "memory");
    __builtin_amdgcn_s_barrier();

    f32x4 acc[4][4] = {};

    for (int s = 0; s < NSK; ++s) {
        const bool pf = (s + 2 < NSK);
        bf16x8 a0[4], a1[4], b0[2], b1[2];

        // ---- phase 0: read all A-subtiles + B-subtiles 0,1 (12 ds_reads) ----
        #pragma unroll
        for (int q = 0; q < 4; ++q) {
            const char* ab = p0 + wm * 8192 + q * 2048 + rowb;
            a0[q] = *(const bf16x8*)(ab + lo0);
            a1[q] = *(const bf16x8*)(ab + lo1);
        }
        #pragma unroll
        for (int j = 0; j < 2; ++j) {
            const char* bb = p0 + A_BYTES + wn * 8192 + j * 2048 + rowb;
            b0[j] = *(const bf16x8*)(bb + lo0);
            b1[j] = *(const bf16x8*)(bb + lo1);
        }
        if (pf) { STG_B0(p2, s + 2); STG_B1(p2, s + 2); STG_B2(p2, s + 2); }
        __builtin_amdgcn_sched_barrier(0);
        __builtin_amdgcn_s_barrier();
        asm volatile("s_waitcnt lgkmcnt(0)" ::: "memory");
        __builtin_amdgcn_sched_barrier(0);
        __builtin_amdgcn_s_setprio(1);
        #pragma unroll
        for (int q = 0; q < 4; ++q)
            #pragma unroll
            for (int j = 0; j < 2; ++j) {
                acc[q][j] = __builtin_amdgcn_mfma_f32_16x16x32_bf16(a0[q], b0[j], acc[q][j], 0, 0, 0);
                acc[q][j] = __builtin_amdgcn_mfma_f32_16x16x32_bf16(a1[q], b1[j], acc[q][j], 0, 0, 0);
            }
        __builtin_amdgcn_s_setprio(0);
        __builtin_amdgcn_sched_barrier(0);
        __builtin_amdgcn_s_barrier();

        // ---- phase 1: read B-subtiles 2,3 (4 ds_reads) ----
        #pragma unroll
        for (int j = 0; j < 2; ++j) {
            const char* bb = p0 + A_BYTES + wn * 8192 + (j + 2) * 2048 + rowb;
            b0[j] = *(const bf16x8*)(bb + lo0);
            b1[j] = *(const bf16x8*)(bb + lo1);
        }
        if (pf) { STG_B3(p2, s + 2); STG_A0(p2, s + 2); STG_A1(p2, s + 2); }
        __builtin_amdgcn_sched_barrier(0);
        __builtin_amdgcn_s_barrier();
        asm volatile("s_waitcnt lgkmcnt(0)" ::: "memory");
        __builtin_amdgcn_sched_barrier(0);
        __builtin_amdgcn_s_setprio(1);
        #pragma unroll
        for (int q = 0; q < 4; ++q)
            #pragma unroll
            for (int j = 0; j < 2; ++j) {
                acc[q][j + 2] = __builtin_amdgcn_mfma_f32_16x16x32_bf16(a0[q], b0[j], acc[q][j + 2], 0, 0, 0);
                acc[q][j + 2] = __builtin_amdgcn_mfma_f32_16x16x32_bf16(a1[q], b1[j], acc[q][j + 2], 0, 0, 0);
            }
        __builtin_amdgcn_s_setprio(0);
        if (pf) asm volatile("s_waitcnt vmcnt(6)" ::: "memory");
        else    asm volatile("s_waitcnt vmcnt(0)" ::: "memory");
        __builtin_amdgcn_sched_barrier(0);
        __builtin_amdgcn_s_barrier();

        char* t = p0; p0 = p1; p1 = p2; p2 = t;
    }

    // epilogue: C = acc + bias
    #pragma unroll
    for (int j = 0; j < 4; ++j) {
        int col = tileN + wn * 64 + j * 16 + (l & 15);
        float bj = bias[col];
        #pragma unroll
        for (int i = 0; i < 4; ++i) {
            int rw = tileM + wm * 64 + i * 16 + (l >> 4) * 4;
            #pragma unroll
            for (int r = 0; r < 4; ++r)
                C[(size_t)(rw + r) * DIM + col] = acc[i][j][r] + bj;
        }
    }
}

extern "C" void kernel_launch(void* const* d_in, const int* in_sizes, int n_in,
                              void* d_out, int out_size, void* d_ws, size_t ws_size,
                              hipStream_t stream) {
    const float* x     = (const float*)d_in[0];
    const int*   rows0 = (const int*)  d_in[1];
    const int*   cols0 = (const int*)  d_in[2];
    const float* vals0 = (const float*)d_in[3];
    const int*   rows1 = (const int*)  d_in[4];
    const int*   cols1 = (const int*)  d_in[5];
    const float* vals1 = (const float*)d_in[6];
    const int*   rows2 = (const int*)  d_in[7];
    const int*   cols2 = (const int*)  d_in[8];
    const float* vals2 = (const float*)d_in[9];
    const float* bias  = (const float*)d_in[10];
    float* out = (float*)d_out;

    char* ws = (char*)d_ws;
    unsigned short* Mc = (unsigned short*)ws;                 // 8 MB
    unsigned short* Xb = (unsigned short*)(ws + 8388608);     // 16 MB
    int*   offb = (int*)(ws + 25165824);      // 3 * 2052
    int*   curb = offb + 3 * 2052;            // 3 * 2048
    int*   colb = curb + 3 * DIM;             // 3 * 16384
    float* valb = (float*)(colb + 3 * NNZc);  // 3 * 16384

    hipMemsetAsync(curb, 0, 3 * DIM * sizeof(int), stream);

    hist_kernel<<<3 * NNZc / NT, NT, 0, stream>>>(rows0, rows1, rows2, curb);
    scan_kernel<<<3, NT, 0, stream>>>(curb, offb);
    scatter_kernel<<<3 * NNZc / NT, NT, 0, stream>>>(rows0, cols0, vals0,
                                                     rows1, cols1, vals1,
                                                     rows2, cols2, vals2,
                                                     curb, colb, valb);
    mcbuild_kernel<<<DIM / RPB, NT, 0, stream>>>(offb, colb, valb, Mc);
    xconv_kernel<<<(BATCH * DIM) / (NT * 8), NT, 0, stream>>>(x, Xb);

    (void)hipFuncSetAttribute((const void*)gemm8,
                              hipFuncAttributeMaxDynamicSharedMemorySize, GEMM_LDS);
    dim3 ggrid(DIM / BN, BATCH / BM);   // 8 x 32 = 256 blocks
    gemm8<<<ggrid, 512, GEMM_LDS, stream>>>(Xb, Mc, bias, out);
}